// Round 1
// baseline (527.827 us; speedup 1.0000x reference)
//
#include <hip/hip_runtime.h>
#include <math.h>

// ---------------------------------------------------------------------------
// MultiHead_CrossAttention: out = (softmax_heads((y@Wq)·(x@Wkv_k)^T/8) @ Wkv_v) @ Wo
// B=4 L=4096 D=1024 H=16 hd=64.  All big GEMMs in bf16 MFMA (threshold is
// 1 bf16-ulp of ref absmax), attention in fp32 on bf16 operands.
// ---------------------------------------------------------------------------

typedef __attribute__((ext_vector_type(8))) short bf16x8;
typedef __attribute__((ext_vector_type(4))) float f32x4;

__device__ __forceinline__ float b2f(short s) {
    union { unsigned u; float f; } x;
    x.u = ((unsigned)(unsigned short)s) << 16;
    return x.f;
}
__device__ __forceinline__ short f2b(float f) {
    union { float f; unsigned u; } x;
    x.f = f;
    unsigned r = (x.u + 0x7FFFu + ((x.u >> 16) & 1u)) >> 16;  // RNE
    return (short)r;
}

// ---- cast fp32 -> bf16 (4 elems/thread, n % 4 == 0) -----------------------
__global__ __launch_bounds__(256) void cast_f32_bf16(
    const float* __restrict__ in, short* __restrict__ out, int n) {
    int i = (blockIdx.x * 256 + threadIdx.x) * 4;
    if (i < n) {
        float4 v = *(const float4*)(in + i);
        short4 o;
        o.x = f2b(v.x); o.y = f2b(v.y); o.z = f2b(v.z); o.w = f2b(v.w);
        *(short4*)(out + i) = o;
    }
}

// ---- transpose + cast: W[K][N] fp32 -> Wt[N][K] bf16 ----------------------
__global__ __launch_bounds__(256) void transpose_cast(
    const float* __restrict__ W, short* __restrict__ Wt, int K, int N) {
    __shared__ float tile[32][33];  // +1 pad breaks bank conflicts
    int tx = threadIdx.x;           // 0..31
    int ty = threadIdx.y;           // 0..7
    int bx = blockIdx.x * 32;       // N offset
    int by = blockIdx.y * 32;       // K offset
#pragma unroll
    for (int j = 0; j < 32; j += 8)
        tile[ty + j][tx] = W[(size_t)(by + ty + j) * N + bx + tx];
    __syncthreads();
#pragma unroll
    for (int j = 0; j < 32; j += 8)
        Wt[(size_t)(bx + ty + j) * K + by + tx] = f2b(tile[tx][ty + j]);
}

// ---- bf16 MFMA GEMM:  C[M][N] = A[M][K] @ Bt[N][K]^T + bias[N] ------------
// BM=BN=128, BK=32. 256 threads = 4 waves, each wave a 64x64 quadrant as a
// 4x4 grid of 16x16x32 MFMA tiles. global_load_lds width=16 staging.
// MFMA frag layouts (verified m89/m120): A/B: idx=lane&15, k=(lane>>4)*8+j;
// C/D: col=lane&15, row=(lane>>4)*4+reg.
#define BM 128
#define BN 128
#define BK 32

#define GLD_LDS(g, l) \
    __builtin_amdgcn_global_load_lds( \
        (const __attribute__((address_space(1))) void*)(g), \
        (__attribute__((address_space(3))) void*)(l), 16, 0, 0)

template <int OUT_BF16>
__global__ __launch_bounds__(256) void gemm_bt(
    const short* __restrict__ A,    // [M][K] bf16
    const short* __restrict__ Bt,   // [N][K] bf16 (pre-transposed weight)
    const float* __restrict__ bias, // [N]
    void* __restrict__ Cout,        // [M][N] bf16 or fp32
    int M, int N, int K) {
    __shared__ short lA[BM * BK];  // 8 KB, row-major [128][32]
    __shared__ short lB[BN * BK];  // 8 KB, row-major [128][32]

    const int tid = threadIdx.x;
    const int bn = blockIdx.x * BN;
    const int bm = blockIdx.y * BM;
    const int lane = tid & 63;
    const int wave = tid >> 6;
    const int wm = (wave & 1) * 64;
    const int wn = (wave >> 1) * 64;
    const int fr = lane & 15;  // frag row (m) / col (n)
    const int kq = lane >> 4;  // k-quad 0..3

    f32x4 acc[4][4];
#pragma unroll
    for (int i = 0; i < 4; ++i)
#pragma unroll
        for (int j = 0; j < 4; ++j) acc[i][j] = (f32x4){0.f, 0.f, 0.f, 0.f};

    // staging: thread t loads 16B at row t/4 (+64 second round), col (t%4)*8
    const int srow = tid >> 2;
    const int scol = (tid & 3) * 8;
    const short* agp = A + (size_t)(bm + srow) * K + scol;
    const short* bgp = Bt + (size_t)(bn + srow) * K + scol;
    const size_t rstep = (size_t)64 * K;

    for (int k0 = 0; k0 < K; k0 += BK) {
        __syncthreads();  // all waves done reading previous tile
        GLD_LDS(agp + k0, &lA[tid * 8]);
        GLD_LDS(agp + k0 + rstep, &lA[2048 + tid * 8]);
        GLD_LDS(bgp + k0, &lB[tid * 8]);
        GLD_LDS(bgp + k0 + rstep, &lB[2048 + tid * 8]);
        __syncthreads();  // vmcnt drained by compiler before barrier

        bf16x8 af[4], bfg[4];
#pragma unroll
        for (int mi = 0; mi < 4; ++mi)
            af[mi] = *(const bf16x8*)&lA[(wm + mi * 16 + fr) * BK + kq * 8];
#pragma unroll
        for (int ni = 0; ni < 4; ++ni)
            bfg[ni] = *(const bf16x8*)&lB[(wn + ni * 16 + fr) * BK + kq * 8];
#pragma unroll
        for (int mi = 0; mi < 4; ++mi)
#pragma unroll
            for (int ni = 0; ni < 4; ++ni)
                acc[mi][ni] = __builtin_amdgcn_mfma_f32_16x16x32_bf16(
                    af[mi], bfg[ni], acc[mi][ni], 0, 0, 0);
    }

    // epilogue: C row = bm+wm+mi*16+kq*4+r, col = bn+wn+ni*16+fr
#pragma unroll
    for (int ni = 0; ni < 4; ++ni) {
        const int col = bn + wn + ni * 16 + fr;
        const float bv = bias[col];
#pragma unroll
        for (int mi = 0; mi < 4; ++mi) {
            const int row0 = bm + wm + mi * 16 + kq * 4;
#pragma unroll
            for (int r = 0; r < 4; ++r) {
                float v = acc[mi][ni][r] + bv;
                if (OUT_BF16)
                    ((short*)Cout)[(size_t)(row0 + r) * N + col] = f2b(v);
                else
                    ((float*)Cout)[(size_t)(row0 + r) * N + col] = v;
            }
        }
    }
}

// ---- attention over heads axis --------------------------------------------
// One thread per (position p, head h). q row: Q[p*1024 + h*64 .. +64).
// k_g = KV[p*2048 + g*128 .. +64), v_g = KV[p*2048 + g*128+64 .. +128).
// s_g = (q . k_g)/8; softmax over g; val = sum_g w_g * v_g.
__global__ __launch_bounds__(256) void attn_kernel(
    const short* __restrict__ Q, const short* __restrict__ KV,
    short* __restrict__ VAL) {
    int t = blockIdx.x * 256 + threadIdx.x;
    size_t p = (size_t)(t >> 4);
    int h = t & 15;

    const short* qp = Q + p * 1024 + h * 64;
    float qh[64];
#pragma unroll
    for (int c = 0; c < 8; ++c) {
        bf16x8 v = ((const bf16x8*)qp)[c];
#pragma unroll
        for (int j = 0; j < 8; ++j) qh[c * 8 + j] = b2f(v[j]);
    }

    const short* kvb = KV + p * 2048;
    float sc[16];
    float mx = -1e30f;
#pragma unroll
    for (int g = 0; g < 16; ++g) {
        const bf16x8* kr = (const bf16x8*)(kvb + g * 128);
        float d = 0.f;
#pragma unroll
        for (int c = 0; c < 8; ++c) {
            bf16x8 kk = kr[c];
#pragma unroll
            for (int j = 0; j < 8; ++j) d += qh[c * 8 + j] * b2f(kk[j]);
        }
        sc[g] = d * 0.125f;
        mx = fmaxf(mx, sc[g]);
    }
    float ssum = 0.f;
#pragma unroll
    for (int g = 0; g < 16; ++g) {
        sc[g] = __expf(sc[g] - mx);
        ssum += sc[g];
    }
    float inv = 1.0f / ssum;

    float vo[64];
#pragma unroll
    for (int j = 0; j < 64; ++j) vo[j] = 0.f;
#pragma unroll
    for (int g = 0; g < 16; ++g) {
        float w = sc[g] * inv;
        const bf16x8* vr = (const bf16x8*)(kvb + g * 128 + 64);
#pragma unroll
        for (int c = 0; c < 8; ++c) {
            bf16x8 vv = vr[c];
#pragma unroll
            for (int j = 0; j < 8; ++j) vo[c * 8 + j] += w * b2f(vv[j]);
        }
    }

    short* op = VAL + p * 1024 + h * 64;
#pragma unroll
    for (int c = 0; c < 8; ++c) {
        bf16x8 o;
#pragma unroll
        for (int j = 0; j < 8; ++j) o[j] = f2b(vo[c * 8 + j]);
        ((bf16x8*)op)[c] = o;
    }
}

// ---------------------------------------------------------------------------
extern "C" void kernel_launch(void* const* d_in, const int* in_sizes, int n_in,
                              void* d_out, int out_size, void* d_ws,
                              size_t ws_size, hipStream_t stream) {
    const float* x = (const float*)d_in[0];
    const float* y = (const float*)d_in[1];
    const float* Wkv = (const float*)d_in[2];
    const float* bkv = (const float*)d_in[3];
    const float* Wq = (const float*)d_in[4];
    const float* bq = (const float*)d_in[5];
    const float* Wo = (const float*)d_in[6];
    const float* bo = (const float*)d_in[7];
    float* out = (float*)d_out;

    const int D = 1024;
    const int M = 16384;  // B*L

    // workspace layout (142.6 MB total)
    char* ws = (char*)d_ws;
    short* Xb = (short*)(ws);                      // M*D bf16      (33.5 MB)
    short* Yb = (short*)(ws + 33554432);           // M*D bf16      (33.5 MB)
    short* Wkvt = (short*)(ws + 67108864);         // 2D*D bf16     (4 MB)
    short* Wqt = (short*)(ws + 71303168);          // D*D bf16      (2 MB)
    short* Wot = (short*)(ws + 73400320);          // D*D bf16      (2 MB)
    short* KV = (short*)(ws + 75497472);           // M*2D bf16     (67 MB)
    short* Q = Xb;    // Xb dead after kv GEMM
    short* VAL = Yb;  // Yb dead after q GEMM

    const int n = M * D;  // 16777216

    cast_f32_bf16<<<n / 1024, 256, 0, stream>>>(x, Xb, n);
    cast_f32_bf16<<<n / 1024, 256, 0, stream>>>(y, Yb, n);
    transpose_cast<<<dim3(2 * D / 32, D / 32), dim3(32, 8), 0, stream>>>(
        Wkv, Wkvt, D, 2 * D);
    transpose_cast<<<dim3(D / 32, D / 32), dim3(32, 8), 0, stream>>>(
        Wq, Wqt, D, D);
    transpose_cast<<<dim3(D / 32, D / 32), dim3(32, 8), 0, stream>>>(
        Wo, Wot, D, D);

    // kv = x @ Wkv + bkv   [16384 x 2048] bf16
    gemm_bt<1><<<dim3(2 * D / BN, M / BM), 256, 0, stream>>>(
        Xb, Wkvt, bkv, KV, M, 2 * D, D);
    // q = y @ Wq + bq      [16384 x 1024] bf16 (into Xb slot)
    gemm_bt<1><<<dim3(D / BN, M / BM), 256, 0, stream>>>(
        Yb, Wqt, bq, Q, M, D, D);
    // attention over heads -> VAL (into Yb slot)
    attn_kernel<<<(M * 16) / 256, 256, 0, stream>>>(Q, KV, VAL);
    // out = val @ Wo + bo  [16384 x 1024] fp32
    gemm_bt<0><<<dim3(D / BN, M / BM), 256, 0, stream>>>(
        VAL, Wot, bo, out, M, D, D);
}

// Round 2
// 453.920 us; speedup vs baseline: 1.1628x; 1.1628x over previous
//
#include <hip/hip_runtime.h>
#include <math.h>

// ---------------------------------------------------------------------------
// MultiHead_CrossAttention: out = (softmax_heads((y@Wq)·(x@Wkv_k)^T/8) @ Wkv_v) @ Wo
// B=4 L=4096 D=1024 H=16 hd=64.  All big GEMMs in bf16 MFMA (threshold is
// 1 bf16-ulp of ref absmax), attention in fp32 on bf16 operands.
// ---------------------------------------------------------------------------

typedef __attribute__((ext_vector_type(8))) short bf16x8;
typedef __attribute__((ext_vector_type(4))) float f32x4;

__device__ __forceinline__ float b2f(short s) {
    union { unsigned u; float f; } x;
    x.u = ((unsigned)(unsigned short)s) << 16;
    return x.f;
}
__device__ __forceinline__ short f2b(float f) {
    union { float f; unsigned u; } x;
    x.f = f;
    unsigned r = (x.u + 0x7FFFu + ((x.u >> 16) & 1u)) >> 16;  // RNE
    return (short)r;
}

// ---- cast fp32 -> bf16 (4 elems/thread, n % 4 == 0) -----------------------
__global__ __launch_bounds__(256) void cast_f32_bf16(
    const float* __restrict__ in, short* __restrict__ out, int n) {
    int i = (blockIdx.x * 256 + threadIdx.x) * 4;
    if (i < n) {
        float4 v = *(const float4*)(in + i);
        short4 o;
        o.x = f2b(v.x); o.y = f2b(v.y); o.z = f2b(v.z); o.w = f2b(v.w);
        *(short4*)(out + i) = o;
    }
}

// ---- transpose + cast: W[K][N] fp32 -> Wt[N][K] bf16 ----------------------
__global__ __launch_bounds__(256) void transpose_cast(
    const float* __restrict__ W, short* __restrict__ Wt, int K, int N) {
    __shared__ float tile[32][33];  // +1 pad breaks bank conflicts
    int tx = threadIdx.x;           // 0..31
    int ty = threadIdx.y;           // 0..7
    int bx = blockIdx.x * 32;       // N offset
    int by = blockIdx.y * 32;       // K offset
#pragma unroll
    for (int j = 0; j < 32; j += 8)
        tile[ty + j][tx] = W[(size_t)(by + ty + j) * N + bx + tx];
    __syncthreads();
#pragma unroll
    for (int j = 0; j < 32; j += 8)
        Wt[(size_t)(bx + ty + j) * K + by + tx] = f2b(tile[tx][ty + j]);
}

// ---- bf16 MFMA GEMM:  C[M][N] = A[M][K] @ Bt[N][K]^T + bias[N] ------------
// BM=BN=128, BK=32. 256 threads = 4 waves, each wave a 64x64 quadrant as a
// 4x4 grid of 16x16x32 MFMA tiles. global_load_lds width=16 staging.
// MFMA frag layouts (verified m89/m120): A/B: idx=lane&15, k=(lane>>4)*8+j;
// C/D: col=lane&15, row=(lane>>4)*4+reg.
#define BM 128
#define BN 128
#define BK 32

#define GLD_LDS(g, l) \
    __builtin_amdgcn_global_load_lds( \
        (const __attribute__((address_space(1))) void*)(g), \
        (__attribute__((address_space(3))) void*)(l), 16, 0, 0)

template <int OUT_BF16>
__global__ __launch_bounds__(256) void gemm_bt(
    const short* __restrict__ A,    // [M][K] bf16
    const short* __restrict__ Bt,   // [N][K] bf16 (pre-transposed weight)
    const float* __restrict__ bias, // [N]
    void* __restrict__ Cout,        // [M][N] bf16 or fp32
    int M, int N, int K) {
    __shared__ short lA[BM * BK];  // 8 KB, row-major [128][32]
    __shared__ short lB[BN * BK];  // 8 KB, row-major [128][32]

    const int tid = threadIdx.x;
    const int bn = blockIdx.x * BN;
    const int bm = blockIdx.y * BM;
    const int lane = tid & 63;
    const int wave = tid >> 6;
    const int wm = (wave & 1) * 64;
    const int wn = (wave >> 1) * 64;
    const int fr = lane & 15;  // frag row (m) / col (n)
    const int kq = lane >> 4;  // k-quad 0..3

    f32x4 acc[4][4];
#pragma unroll
    for (int i = 0; i < 4; ++i)
#pragma unroll
        for (int j = 0; j < 4; ++j) acc[i][j] = (f32x4){0.f, 0.f, 0.f, 0.f};

    // staging: thread t loads 16B at row t/4 (+64 second round), col (t%4)*8
    const int srow = tid >> 2;
    const int scol = (tid & 3) * 8;
    const short* agp = A + (size_t)(bm + srow) * K + scol;
    const short* bgp = Bt + (size_t)(bn + srow) * K + scol;
    const size_t rstep = (size_t)64 * K;

    for (int k0 = 0; k0 < K; k0 += BK) {
        __syncthreads();  // all waves done reading previous tile
        GLD_LDS(agp + k0, &lA[tid * 8]);
        GLD_LDS(agp + k0 + rstep, &lA[2048 + tid * 8]);
        GLD_LDS(bgp + k0, &lB[tid * 8]);
        GLD_LDS(bgp + k0 + rstep, &lB[2048 + tid * 8]);
        __syncthreads();  // vmcnt drained by compiler before barrier

        bf16x8 af[4], bfg[4];
#pragma unroll
        for (int mi = 0; mi < 4; ++mi)
            af[mi] = *(const bf16x8*)&lA[(wm + mi * 16 + fr) * BK + kq * 8];
#pragma unroll
        for (int ni = 0; ni < 4; ++ni)
            bfg[ni] = *(const bf16x8*)&lB[(wn + ni * 16 + fr) * BK + kq * 8];
#pragma unroll
        for (int mi = 0; mi < 4; ++mi)
#pragma unroll
            for (int ni = 0; ni < 4; ++ni)
                acc[mi][ni] = __builtin_amdgcn_mfma_f32_16x16x32_bf16(
                    af[mi], bfg[ni], acc[mi][ni], 0, 0, 0);
    }

    // epilogue: C row = bm+wm+mi*16+kq*4+r, col = bn+wn+ni*16+fr
#pragma unroll
    for (int ni = 0; ni < 4; ++ni) {
        const int col = bn + wn + ni * 16 + fr;
        const float bv = bias[col];
#pragma unroll
        for (int mi = 0; mi < 4; ++mi) {
            const int row0 = bm + wm + mi * 16 + kq * 4;
#pragma unroll
            for (int r = 0; r < 4; ++r) {
                float v = acc[mi][ni][r] + bv;
                if (OUT_BF16)
                    ((short*)Cout)[(size_t)(row0 + r) * N + col] = f2b(v);
                else
                    ((float*)Cout)[(size_t)(row0 + r) * N + col] = v;
            }
        }
    }
}

// ---- attention over heads axis, one wave per position ---------------------
// lane i owns dims [i*16, i*16+16) of the 1024-wide row: h = lane>>2 (head),
// dq = lane&3 (16-dim chunk within the head).
// s[g] = (q_h . k_g)/8 reduced across the 4 dq-lanes via shfl_xor(1,2);
// softmax over g per lane (replicated x4, free); vo = sum_g w_g * v_g[chunk].
// q load/VAL store are 32 B/lane fully coalesced (2 KB/wave contiguous).
__global__ __launch_bounds__(256) void attn_kernel(
    const short* __restrict__ Q, const short* __restrict__ KV,
    short* __restrict__ VAL) {
    const int wave = threadIdx.x >> 6;
    const int lane = threadIdx.x & 63;
    const size_t p = (size_t)blockIdx.x * 4 + wave;
    const int dq = lane & 3;

    // q chunk: 16 bf16 at Q[p*1024 + lane*16]
    const bf16x8* qp = (const bf16x8*)(Q + p * 1024 + (size_t)lane * 16);
    bf16x8 q0 = qp[0], q1 = qp[1];
    float q[16];
#pragma unroll
    for (int j = 0; j < 8; ++j) {
        q[j] = b2f(q0[j]);
        q[8 + j] = b2f(q1[j]);
    }

    const short* kvb = KV + p * 2048;

    // partial scores over this lane's 16 dims, for all 16 key-heads g
    float s[16];
#pragma unroll
    for (int g = 0; g < 16; ++g) {
        const bf16x8* kp = (const bf16x8*)(kvb + g * 128 + dq * 16);
        bf16x8 k0 = kp[0], k1 = kp[1];
        float d = 0.f;
#pragma unroll
        for (int j = 0; j < 8; ++j) {
            d += q[j] * b2f(k0[j]);
            d += q[8 + j] * b2f(k1[j]);
        }
        s[g] = d;
    }
    // reduce across the 4 dq-lanes (bits 0..1 of lane), then scale
    float mx = -1e30f;
#pragma unroll
    for (int g = 0; g < 16; ++g) {
        s[g] += __shfl_xor(s[g], 1, 64);
        s[g] += __shfl_xor(s[g], 2, 64);
        s[g] *= 0.125f;
        mx = fmaxf(mx, s[g]);
    }
    float ssum = 0.f;
#pragma unroll
    for (int g = 0; g < 16; ++g) {
        s[g] = __expf(s[g] - mx);
        ssum += s[g];
    }
    const float inv = 1.0f / ssum;

    float vo[16];
#pragma unroll
    for (int j = 0; j < 16; ++j) vo[j] = 0.f;
#pragma unroll
    for (int g = 0; g < 16; ++g) {
        const float w = s[g] * inv;
        const bf16x8* vp = (const bf16x8*)(kvb + g * 128 + 64 + dq * 16);
        bf16x8 v0 = vp[0], v1 = vp[1];
#pragma unroll
        for (int j = 0; j < 8; ++j) {
            vo[j] += w * b2f(v0[j]);
            vo[8 + j] += w * b2f(v1[j]);
        }
    }

    bf16x8 o0, o1;
#pragma unroll
    for (int j = 0; j < 8; ++j) {
        o0[j] = f2b(vo[j]);
        o1[j] = f2b(vo[8 + j]);
    }
    bf16x8* op = (bf16x8*)(VAL + p * 1024 + (size_t)lane * 16);
    op[0] = o0;
    op[1] = o1;
}

// ---------------------------------------------------------------------------
extern "C" void kernel_launch(void* const* d_in, const int* in_sizes, int n_in,
                              void* d_out, int out_size, void* d_ws,
                              size_t ws_size, hipStream_t stream) {
    const float* x = (const float*)d_in[0];
    const float* y = (const float*)d_in[1];
    const float* Wkv = (const float*)d_in[2];
    const float* bkv = (const float*)d_in[3];
    const float* Wq = (const float*)d_in[4];
    const float* bq = (const float*)d_in[5];
    const float* Wo = (const float*)d_in[6];
    const float* bo = (const float*)d_in[7];
    float* out = (float*)d_out;

    const int D = 1024;
    const int M = 16384;  // B*L

    // workspace layout (142.6 MB total)
    char* ws = (char*)d_ws;
    short* Xb = (short*)(ws);                      // M*D bf16      (33.5 MB)
    short* Yb = (short*)(ws + 33554432);           // M*D bf16      (33.5 MB)
    short* Wkvt = (short*)(ws + 67108864);         // 2D*D bf16     (4 MB)
    short* Wqt = (short*)(ws + 71303168);          // D*D bf16      (2 MB)
    short* Wot = (short*)(ws + 73400320);          // D*D bf16      (2 MB)
    short* KV = (short*)(ws + 75497472);           // M*2D bf16     (67 MB)
    short* Q = Xb;    // Xb dead after kv GEMM
    short* VAL = Yb;  // Yb dead after q GEMM

    const int n = M * D;  // 16777216

    cast_f32_bf16<<<n / 1024, 256, 0, stream>>>(x, Xb, n);
    cast_f32_bf16<<<n / 1024, 256, 0, stream>>>(y, Yb, n);
    transpose_cast<<<dim3(2 * D / 32, D / 32), dim3(32, 8), 0, stream>>>(
        Wkv, Wkvt, D, 2 * D);
    transpose_cast<<<dim3(D / 32, D / 32), dim3(32, 8), 0, stream>>>(
        Wq, Wqt, D, D);
    transpose_cast<<<dim3(D / 32, D / 32), dim3(32, 8), 0, stream>>>(
        Wo, Wot, D, D);

    // kv = x @ Wkv + bkv   [16384 x 2048] bf16
    gemm_bt<1><<<dim3(2 * D / BN, M / BM), 256, 0, stream>>>(
        Xb, Wkvt, bkv, KV, M, 2 * D, D);
    // q = y @ Wq + bq      [16384 x 1024] bf16 (into Xb slot)
    gemm_bt<1><<<dim3(D / BN, M / BM), 256, 0, stream>>>(
        Yb, Wqt, bq, Q, M, D, D);
    // attention over heads -> VAL (into Yb slot)
    attn_kernel<<<M / 4, 256, 0, stream>>>(Q, KV, VAL);
    // out = val @ Wo + bo  [16384 x 1024] fp32
    gemm_bt<0><<<dim3(D / BN, M / BM), 256, 0, stream>>>(
        VAL, Wot, bo, out, M, D, D);
}

// Round 3
// 428.178 us; speedup vs baseline: 1.2327x; 1.0601x over previous
//
#include <hip/hip_runtime.h>
#include <math.h>

// ---------------------------------------------------------------------------
// MultiHead_CrossAttention: out = (softmax_heads((y@Wq)·(x@Wkv_k)^T/8) @ Wkv_v) @ Wo
// B=4 L=4096 D=1024 H=16 hd=64.  All big GEMMs in bf16 MFMA (threshold is
// 1 bf16-ulp of ref absmax), attention in fp32 on bf16 operands.
// R3: XCD-aware block swizzle in gemm_bt (same-A-panel blocks -> same XCD),
//     fused cast launch, fused Wq/Wo transpose launch.
// ---------------------------------------------------------------------------

typedef __attribute__((ext_vector_type(8))) short bf16x8;
typedef __attribute__((ext_vector_type(4))) float f32x4;

__device__ __forceinline__ float b2f(short s) {
    union { unsigned u; float f; } x;
    x.u = ((unsigned)(unsigned short)s) << 16;
    return x.f;
}
__device__ __forceinline__ short f2b(float f) {
    union { float f; unsigned u; } x;
    x.f = f;
    unsigned r = (x.u + 0x7FFFu + ((x.u >> 16) & 1u)) >> 16;  // RNE
    return (short)r;
}

// ---- cast fp32 -> bf16 for two tensors in one launch ----------------------
__global__ __launch_bounds__(256) void cast2_f32_bf16(
    const float* __restrict__ in0, short* __restrict__ out0,
    const float* __restrict__ in1, short* __restrict__ out1, int n) {
    int i = (blockIdx.x * 256 + threadIdx.x) * 4;
    const float* in = in0;
    short* out = out0;
    if (i >= n) {
        i -= n;
        in = in1;
        out = out1;
    }
    float4 v = *(const float4*)(in + i);
    short4 o;
    o.x = f2b(v.x); o.y = f2b(v.y); o.z = f2b(v.z); o.w = f2b(v.w);
    *(short4*)(out + i) = o;
}

// ---- transpose + cast: W[K][N] fp32 -> Wt[N][K] bf16 ----------------------
// blockIdx.z selects among up to 2 (src,dst) pairs of identical shape.
__global__ __launch_bounds__(256) void transpose_cast2(
    const float* __restrict__ W0, short* __restrict__ Wt0,
    const float* __restrict__ W1, short* __restrict__ Wt1, int K, int N) {
    const float* W = blockIdx.z ? W1 : W0;
    short* Wt = blockIdx.z ? Wt1 : Wt0;
    __shared__ float tile[32][33];  // +1 pad breaks bank conflicts
    int tx = threadIdx.x;           // 0..31
    int ty = threadIdx.y;           // 0..7
    int bx = blockIdx.x * 32;       // N offset
    int by = blockIdx.y * 32;       // K offset
#pragma unroll
    for (int j = 0; j < 32; j += 8)
        tile[ty + j][tx] = W[(size_t)(by + ty + j) * N + bx + tx];
    __syncthreads();
#pragma unroll
    for (int j = 0; j < 32; j += 8)
        Wt[(size_t)(bx + ty + j) * K + by + tx] = f2b(tile[tx][ty + j]);
}

// ---- bf16 MFMA GEMM:  C[M][N] = A[M][K] @ Bt[N][K]^T + bias[N] ------------
// BM=BN=128, BK=32. 256 threads = 4 waves, each wave a 64x64 quadrant as a
// 4x4 grid of 16x16x32 MFMA tiles. global_load_lds width=16 staging.
// MFMA frag layouts (verified m89/m120): A/B: idx=lane&15, k=(lane>>4)*8+j;
// C/D: col=lane&15, row=(lane>>4)*4+reg.
// XCD swizzle: workgroup->XCD is ~linear%8 (m09). Remap linear id so all
// blocks sharing an A row-panel (same by) get lin%8 == by%8 -> one XCD's L2
// fetches each A panel exactly once from HBM.
#define BM 128
#define BN 128
#define BK 32

#define GLD_LDS(g, l) \
    __builtin_amdgcn_global_load_lds( \
        (const __attribute__((address_space(1))) void*)(g), \
        (__attribute__((address_space(3))) void*)(l), 16, 0, 0)

template <int OUT_BF16>
__global__ __launch_bounds__(256) void gemm_bt(
    const short* __restrict__ A,    // [M][K] bf16
    const short* __restrict__ Bt,   // [N][K] bf16 (pre-transposed weight)
    const float* __restrict__ bias, // [N]
    void* __restrict__ Cout,        // [M][N] bf16 or fp32
    int M, int N, int K) {
    __shared__ short lA[BM * BK];  // 8 KB, row-major [128][32]
    __shared__ short lB[BN * BK];  // 8 KB, row-major [128][32]

    const int tid = threadIdx.x;

    // XCD-aware swizzle (gridDim.y % 8 == 0 for all our shapes)
    const int NX = gridDim.x;
    int bxi, byi;
    {
        int lin = blockIdx.y * NX + blockIdx.x;
        int xcd = lin & 7;
        int j = lin >> 3;
        bxi = j % NX;
        byi = (j / NX) * 8 + xcd;
    }
    const int bn = bxi * BN;
    const int bm = byi * BM;

    const int lane = tid & 63;
    const int wave = tid >> 6;
    const int wm = (wave & 1) * 64;
    const int wn = (wave >> 1) * 64;
    const int fr = lane & 15;  // frag row (m) / col (n)
    const int kq = lane >> 4;  // k-quad 0..3

    f32x4 acc[4][4];
#pragma unroll
    for (int i = 0; i < 4; ++i)
#pragma unroll
        for (int j = 0; j < 4; ++j) acc[i][j] = (f32x4){0.f, 0.f, 0.f, 0.f};

    // staging: thread t loads 16B at row t/4 (+64 second round), col (t%4)*8
    const int srow = tid >> 2;
    const int scol = (tid & 3) * 8;
    const short* agp = A + (size_t)(bm + srow) * K + scol;
    const short* bgp = Bt + (size_t)(bn + srow) * K + scol;
    const size_t rstep = (size_t)64 * K;

    for (int k0 = 0; k0 < K; k0 += BK) {
        __syncthreads();  // all waves done reading previous tile
        GLD_LDS(agp + k0, &lA[tid * 8]);
        GLD_LDS(agp + k0 + rstep, &lA[2048 + tid * 8]);
        GLD_LDS(bgp + k0, &lB[tid * 8]);
        GLD_LDS(bgp + k0 + rstep, &lB[2048 + tid * 8]);
        __syncthreads();  // vmcnt drained by compiler before barrier

        bf16x8 af[4], bfg[4];
#pragma unroll
        for (int mi = 0; mi < 4; ++mi)
            af[mi] = *(const bf16x8*)&lA[(wm + mi * 16 + fr) * BK + kq * 8];
#pragma unroll
        for (int ni = 0; ni < 4; ++ni)
            bfg[ni] = *(const bf16x8*)&lB[(wn + ni * 16 + fr) * BK + kq * 8];
#pragma unroll
        for (int mi = 0; mi < 4; ++mi)
#pragma unroll
            for (int ni = 0; ni < 4; ++ni)
                acc[mi][ni] = __builtin_amdgcn_mfma_f32_16x16x32_bf16(
                    af[mi], bfg[ni], acc[mi][ni], 0, 0, 0);
    }

    // epilogue: C row = bm+wm+mi*16+kq*4+r, col = bn+wn+ni*16+fr
#pragma unroll
    for (int ni = 0; ni < 4; ++ni) {
        const int col = bn + wn + ni * 16 + fr;
        const float bv = bias[col];
#pragma unroll
        for (int mi = 0; mi < 4; ++mi) {
            const int row0 = bm + wm + mi * 16 + kq * 4;
#pragma unroll
            for (int r = 0; r < 4; ++r) {
                float v = acc[mi][ni][r] + bv;
                if (OUT_BF16)
                    ((short*)Cout)[(size_t)(row0 + r) * N + col] = f2b(v);
                else
                    ((float*)Cout)[(size_t)(row0 + r) * N + col] = v;
            }
        }
    }
}

// ---- attention over heads axis, one wave per position ---------------------
// lane i owns dims [i*16, i*16+16): h = lane>>2 (head), dq = lane&3.
// s[g] = (q_h . k_g)/8 reduced across the 4 dq-lanes via shfl_xor(1,2);
// softmax over g per lane (replicated x4, free); vo = sum_g w_g * v_g[chunk].
__global__ __launch_bounds__(256) void attn_kernel(
    const short* __restrict__ Q, const short* __restrict__ KV,
    short* __restrict__ VAL) {
    const int wave = threadIdx.x >> 6;
    const int lane = threadIdx.x & 63;
    const size_t p = (size_t)blockIdx.x * 4 + wave;
    const int dq = lane & 3;

    const bf16x8* qp = (const bf16x8*)(Q + p * 1024 + (size_t)lane * 16);
    bf16x8 q0 = qp[0], q1 = qp[1];
    float q[16];
#pragma unroll
    for (int j = 0; j < 8; ++j) {
        q[j] = b2f(q0[j]);
        q[8 + j] = b2f(q1[j]);
    }

    const short* kvb = KV + p * 2048;

    float s[16];
#pragma unroll
    for (int g = 0; g < 16; ++g) {
        const bf16x8* kp = (const bf16x8*)(kvb + g * 128 + dq * 16);
        bf16x8 k0 = kp[0], k1 = kp[1];
        float d = 0.f;
#pragma unroll
        for (int j = 0; j < 8; ++j) {
            d += q[j] * b2f(k0[j]);
            d += q[8 + j] * b2f(k1[j]);
        }
        s[g] = d;
    }
    float mx = -1e30f;
#pragma unroll
    for (int g = 0; g < 16; ++g) {
        s[g] += __shfl_xor(s[g], 1, 64);
        s[g] += __shfl_xor(s[g], 2, 64);
        s[g] *= 0.125f;
        mx = fmaxf(mx, s[g]);
    }
    float ssum = 0.f;
#pragma unroll
    for (int g = 0; g < 16; ++g) {
        s[g] = __expf(s[g] - mx);
        ssum += s[g];
    }
    const float inv = 1.0f / ssum;

    float vo[16];
#pragma unroll
    for (int j = 0; j < 16; ++j) vo[j] = 0.f;
#pragma unroll
    for (int g = 0; g < 16; ++g) {
        const float w = s[g] * inv;
        const bf16x8* vp = (const bf16x8*)(kvb + g * 128 + 64 + dq * 16);
        bf16x8 v0 = vp[0], v1 = vp[1];
#pragma unroll
        for (int j = 0; j < 8; ++j) {
            vo[j] += w * b2f(v0[j]);
            vo[8 + j] += w * b2f(v1[j]);
        }
    }

    bf16x8 o0, o1;
#pragma unroll
    for (int j = 0; j < 8; ++j) {
        o0[j] = f2b(vo[j]);
        o1[j] = f2b(vo[8 + j]);
    }
    bf16x8* op = (bf16x8*)(VAL + p * 1024 + (size_t)lane * 16);
    op[0] = o0;
    op[1] = o1;
}

// ---------------------------------------------------------------------------
extern "C" void kernel_launch(void* const* d_in, const int* in_sizes, int n_in,
                              void* d_out, int out_size, void* d_ws,
                              size_t ws_size, hipStream_t stream) {
    const float* x = (const float*)d_in[0];
    const float* y = (const float*)d_in[1];
    const float* Wkv = (const float*)d_in[2];
    const float* bkv = (const float*)d_in[3];
    const float* Wq = (const float*)d_in[4];
    const float* bq = (const float*)d_in[5];
    const float* Wo = (const float*)d_in[6];
    const float* bo = (const float*)d_in[7];
    float* out = (float*)d_out;

    const int D = 1024;
    const int M = 16384;  // B*L

    // workspace layout (142.6 MB total)
    char* ws = (char*)d_ws;
    short* Xb = (short*)(ws);                      // M*D bf16      (33.5 MB)
    short* Yb = (short*)(ws + 33554432);           // M*D bf16      (33.5 MB)
    short* Wkvt = (short*)(ws + 67108864);         // 2D*D bf16     (4 MB)
    short* Wqt = (short*)(ws + 71303168);          // D*D bf16      (2 MB)
    short* Wot = (short*)(ws + 73400320);          // D*D bf16      (2 MB)
    short* KV = (short*)(ws + 75497472);           // M*2D bf16     (67 MB)
    short* Q = Xb;    // Xb dead after kv GEMM
    short* VAL = Yb;  // Yb dead after q GEMM

    const int n = M * D;  // 16777216

    cast2_f32_bf16<<<2 * n / 1024, 256, 0, stream>>>(x, Xb, y, Yb, n);
    transpose_cast2<<<dim3(2 * D / 32, D / 32, 1), dim3(32, 8), 0, stream>>>(
        Wkv, Wkvt, (const float*)0, (short*)0, D, 2 * D);
    transpose_cast2<<<dim3(D / 32, D / 32, 2), dim3(32, 8), 0, stream>>>(
        Wq, Wqt, Wo, Wot, D, D);

    // kv = x @ Wkv + bkv   [16384 x 2048] bf16
    gemm_bt<1><<<dim3(2 * D / BN, M / BM), 256, 0, stream>>>(
        Xb, Wkvt, bkv, KV, M, 2 * D, D);
    // q = y @ Wq + bq      [16384 x 1024] bf16 (into Xb slot)
    gemm_bt<1><<<dim3(D / BN, M / BM), 256, 0, stream>>>(
        Yb, Wqt, bq, Q, M, D, D);
    // attention over heads -> VAL (into Yb slot)
    attn_kernel<<<M / 4, 256, 0, stream>>>(Q, KV, VAL);
    // out = val @ Wo + bo  [16384 x 1024] fp32
    gemm_bt<0><<<dim3(D / BN, M / BM), 256, 0, stream>>>(
        VAL, Wot, bo, out, M, D, D);
}